// Round 5
// baseline (1342.313 us; speedup 1.0000x reference)
//
#include <hip/hip_runtime.h>

// GRU encoder: B=64, T=256, U=1024, VOCAB=10000. All float tensors are FP32.
// GEMM on bf16 MFMA (RNE-converted inputs); h carry stays exact f32 in a
// per-thread register. ONE persistent kernel; W_rec fragments resident in
// registers for all 256 steps. Cross-block handoff: SINGLE-WORD tagged
// publish {step_tag:16 | bf16(h):16}, sc0 sc1 write-through, no fences.
//
// Round-5 change: SAMPLE-THEN-VERIFY poll. Round 4's spin loop reloaded the
// full A-slice every iteration (16 MB/device-sweep -> LLC saturation, the
// measured 3.9 us/step). Now the spin loop reads ONE tagged dword per
// (lane, producer-slice) — 32 B/lane, 32x less — and only on sample match
// does the full load + full tag verify (correctness never rests on the
// sample). Plus fast gate math and v_perm A-packing on the publish chain.
#define BB 64
#define TT 256
#define UU 1024
#define NG 3072

typedef __attribute__((ext_vector_type(8))) __bf16 bf16x8;
typedef __attribute__((ext_vector_type(4))) float f32x4;

__device__ __forceinline__ unsigned short f2bf(float f) {
    union { unsigned int i; float f; } c; c.f = f;
    unsigned int r = c.i + 0x7FFFu + ((c.i >> 16) & 1u);  // RNE
    return (unsigned short)(r >> 16);
}

__device__ __forceinline__ float fsigm(float xv) {
    // fast sigmoid: err ~1e-7 abs, far under the bf16 handoff quantization
    return __fdividef(1.f, 1.f + __expf(-xv));
}

union U16x8 { unsigned short us[8]; uint4 u4; };

// ---------------------------------------------------------------------------
// Pack W_rec (f32) into bf16 MFMA B-fragment order (unchanged, verified).
// Total 6 MB.
// ---------------------------------------------------------------------------
__global__ __launch_bounds__(256) void pack_kernel(
    const float* __restrict__ w_rec,    // (1024, 3072) f32
    uint4* __restrict__ wpack)
{
    const int tid  = threadIdx.x;
    const int kc   = tid >> 6;
    const int lane = tid & 63;
    const int l16  = lane & 15;
    const int quad = lane >> 4;
    const int cj   = blockIdx.x;            // 0..63
    const int colb = (cj << 4) + l16;

    #pragma unroll
    for (int g = 0; g < 3; ++g) {
        #pragma unroll
        for (int s = 0; s < 8; ++s) {
            const int kb = (kc << 8) + (s << 5) + (quad << 3);
            U16x8 c;
            #pragma unroll
            for (int j = 0; j < 8; ++j)
                c.us[j] = f2bf(w_rec[(size_t)(kb + j) * NG + g * UU + colb]);
            wpack[(size_t)(((cj * 4 + kc) * 24) + g * 8 + s) * 64 + lane] = c.u4;
        }
    }
}

// Seed: parity 0 = {tag 0 | bf16(hidden)}; parity 1 poisoned with tag 0xFFFF
// so graph replays never see a stale matching tag.
__global__ __launch_bounds__(256) void seed_kernel(
    const float* __restrict__ hidden,       // (64, 1024) f32
    unsigned int* __restrict__ hbuf32)
{
    const int i = blockIdx.x * 256 + threadIdx.x;   // 65536 elements
    hbuf32[i] = (unsigned int)f2bf(hidden[i]);      // tag 0 in high half
    hbuf32[BB * UU + i] = 0xFFFF0000u;              // invalid tag
}

// ---------------------------------------------------------------------------
// Persistent GRU kernel. 256 blocks x 256 threads, 1 block/CU.
// block = (ri, cj): ri = batch rowgroup (4 x 16 rows), cj = unit colgroup
// (64 x 16 cols). Waves K-split (4 x 256). Step t consumes parity t&1 words
// tagged t; step t produces parity (t+1)&1 words tagged t+1.
// ---------------------------------------------------------------------------
__global__ __launch_bounds__(256) void gru_kernel(
    const int* __restrict__ x,              // (64, 256) int32
    const float* __restrict__ hidden,       // (64, 1024) f32
    const float* __restrict__ w_in,         // (10000, 3072) f32
    const float* __restrict__ b_in,         // (3072,) f32
    const float* __restrict__ b_rec,        // (3072,) f32
    const uint4* __restrict__ wpack,        // packed W_rec bf16 frags
    float* __restrict__ out,                // (64,256,1024) + (64,1024) f32
    unsigned int* __restrict__ hbuf32)      // ws: 2 x 64 x 1024 tagged u32
{
    const int tid  = threadIdx.x;
    const int wave = tid >> 6;        // K-chunk 0..3
    const int lane = tid & 63;
    const int l16  = lane & 15;
    const int quad = lane >> 4;

    const int ri   = blockIdx.x >> 6;  // 0..3
    const int cj   = blockIdx.x & 63;  // 0..63
    const int row0 = ri << 4;
    const int col0 = cj << 4;

    // parity-double-buffered K-reduction scratch (one barrier per step)
    __align__(16) __shared__ float red[2][4][3][64][4];   // 24 KB

    // ---- B-fragments: loaded ONCE, resident for all 256 steps ----
    const uint4* wp = wpack + (size_t)((cj * 4 + wave) * 24) * 64 + lane;
    uint4 wf[3][8];
    #pragma unroll
    for (int g = 0; g < 3; ++g)
        #pragma unroll
        for (int s = 0; s < 8; ++s)
            wf[g][s] = wp[(g * 8 + s) * 64];

    // ---- per-thread gate element (fixed for the whole sequence) ----
    const int em = tid >> 4;
    const int en = tid & 15;
    const int gb = row0 + em;
    const int gu = col0 + en;
    // C/D layout (col=lane&15, row=(lane>>4)*4+reg) -> source lane/reg
    const int rl = ((em >> 2) << 4) | en;
    const int rr = em & 3;

    // loop-invariant biases
    const float bz  = b_in[gu]          + b_rec[gu];
    const float br  = b_in[UU + gu]     + b_rec[UU + gu];
    const float bih = b_in[2 * UU + gu];
    const float brh = b_rec[2 * UU + gu];

    // exact f32 h carry in a register
    float h = hidden[gb * UU + gu];

    const int* xrow = x + gb * TT;

    const unsigned int* a0 = hbuf32 + (size_t)(row0 + l16) * UU
                           + (wave << 8) + (quad << 3);         // parity 0 A base
    const unsigned int* a1 = a0 + (size_t)BB * UU;              // parity 1
    unsigned int* hb0 = hbuf32 + (size_t)gb * UU + gu;          // parity 0 slot
    unsigned int* hb1 = hb0 + (size_t)BB * UU;                  // parity 1
    float* orow = out + (size_t)gb * TT * UU + gu;

    // embedding gather for t=0 (plain cached loads)
    size_t wrow = (size_t)xrow[0] * NG;
    float wz = w_in[wrow + gu];
    float wr = w_in[wrow + UU + gu];
    float wh = w_in[wrow + 2 * UU + gu];

    for (int t = 0; t < TT; ++t) {
        // ---- SAMPLE-THEN-VERIFY data-poll. Spin phase reads 1 tagged dword
        // per producer-slice (8 dwords/lane, 32 B) instead of the full 256 B.
        // Each lane's s-th dwordx4 pair comes from a single producer block;
        // one fresh word gates the full load, whose tags are ALL re-verified
        // (retry on failure), so correctness never rests on the sample. ----
        const unsigned int texp = (unsigned int)t << 16;
        const unsigned int* arow = (t & 1) ? a1 : a0;
        uint4 q[16];
        for (;;) {
            unsigned int smp[8];
            #pragma unroll
            for (int s = 0; s < 8; ++s)
                asm volatile("global_load_dword %0, %1, off sc0 sc1"
                             : "=v"(smp[s]) : "v"(arow + (s << 5) + 7));
            asm volatile("s_waitcnt vmcnt(0)" ::: "memory");
            unsigned int sa = 0;
            #pragma unroll
            for (int s = 0; s < 8; ++s) sa |= smp[s] ^ texp;
            if (!__all((sa & 0xFFFF0000u) == 0u)) continue;

            // full load + full verify
            #pragma unroll
            for (int s = 0; s < 8; ++s) {
                asm volatile("global_load_dwordx4 %0, %1, off sc0 sc1"
                             : "=v"(q[2 * s])     : "v"(arow + (s << 5)));
                asm volatile("global_load_dwordx4 %0, %1, off sc0 sc1"
                             : "=v"(q[2 * s + 1]) : "v"(arow + (s << 5) + 4));
            }
            asm volatile("s_waitcnt vmcnt(0)" ::: "memory");
            unsigned int va = 0;
            #pragma unroll
            for (int i = 0; i < 16; ++i)
                va |= (q[i].x ^ texp) | (q[i].y ^ texp)
                    | (q[i].z ^ texp) | (q[i].w ^ texp);
            if (__all((va & 0xFFFF0000u) == 0u)) break;
        }
        __builtin_amdgcn_sched_barrier(0);

        // ---- pack low halves into MFMA A fragments (v_perm: 1 op/word) ----
        f32x4 acc0 = {0.f, 0.f, 0.f, 0.f};
        f32x4 acc1 = {0.f, 0.f, 0.f, 0.f};
        f32x4 acc2 = {0.f, 0.f, 0.f, 0.f};
        #pragma unroll
        for (int s = 0; s < 8; ++s) {
            const uint4 lo = q[2 * s];
            const uint4 hi = q[2 * s + 1];
            uint4 aw;
            aw.x = __builtin_amdgcn_perm(lo.y, lo.x, 0x05040100u);
            aw.y = __builtin_amdgcn_perm(lo.w, lo.z, 0x05040100u);
            aw.z = __builtin_amdgcn_perm(hi.y, hi.x, 0x05040100u);
            aw.w = __builtin_amdgcn_perm(hi.w, hi.z, 0x05040100u);
            const bf16x8 a = __builtin_bit_cast(bf16x8, aw);
            acc0 = __builtin_amdgcn_mfma_f32_16x16x32_bf16(
                a, __builtin_bit_cast(bf16x8, wf[0][s]), acc0, 0, 0, 0);
            acc1 = __builtin_amdgcn_mfma_f32_16x16x32_bf16(
                a, __builtin_bit_cast(bf16x8, wf[1][s]), acc1, 0, 0, 0);
            acc2 = __builtin_amdgcn_mfma_f32_16x16x32_bf16(
                a, __builtin_bit_cast(bf16x8, wf[2][s]), acc2, 0, 0, 0);
        }

        // ---- cross-wave K reduction through LDS (parity-buffered) ----
        const int p = t & 1;
        *(f32x4*)&red[p][wave][0][lane][0] = acc0;
        *(f32x4*)&red[p][wave][1][lane][0] = acc1;
        *(f32x4*)&red[p][wave][2][lane][0] = acc2;
        __syncthreads();

        const float rz = red[p][0][0][rl][rr] + red[p][1][0][rl][rr]
                       + red[p][2][0][rl][rr] + red[p][3][0][rl][rr];
        const float rrv = red[p][0][1][rl][rr] + red[p][1][1][rl][rr]
                        + red[p][2][1][rl][rr] + red[p][3][1][rl][rr];
        const float rh = red[p][0][2][rl][rr] + red[p][1][2][rl][rr]
                       + red[p][2][2][rl][rr] + red[p][3][2][rl][rr];

        // fast gates (publish chain): sigmoid via __expf, tanh = 2*sigm(2x)-1
        const float z  = fsigm(wz + rz + bz);
        const float r  = fsigm(wr + rrv + br);
        const float th = wh + bih + r * (rh + brh);
        const float hh = 2.f * fsigm(2.f * th) - 1.f;
        h = z * h + (1.f - z) * hh;

        // ---- publish FIRST (critical path): single tagged word, no drain ----
        if (t < TT - 1) {
            const unsigned int hv = ((unsigned int)(t + 1) << 16)
                                  | (unsigned int)f2bf(h);
            unsigned int* hs = (t & 1) ? hb0 : hb1;   // parity (t+1)&1
            asm volatile("global_store_dword %0, %1, off sc0 sc1"
                         :: "v"(hs), "v"(hv) : "memory");
        }

        // ---- background: out row + next embedding gather (off the chain) ----
        orow[(size_t)t * UU] = h;
        if (t < TT - 1) {
            wrow = (size_t)xrow[t + 1] * NG;
            wz = w_in[wrow + gu];
            wr = w_in[wrow + UU + gu];
            wh = w_in[wrow + 2 * UU + gu];
        }
    }

    // final state
    out[(size_t)BB * TT * UU + (size_t)gb * UU + gu] = h;
}

extern "C" void kernel_launch(void* const* d_in, const int* in_sizes, int n_in,
                              void* d_out, int out_size, void* d_ws, size_t ws_size,
                              hipStream_t stream) {
    const int* x        = (const int*)d_in[0];
    const float* hidden = (const float*)d_in[1];
    const float* w_in   = (const float*)d_in[2];
    const float* w_rec  = (const float*)d_in[3];
    const float* b_in   = (const float*)d_in[4];
    const float* b_rec  = (const float*)d_in[5];
    float* out          = (float*)d_out;

    unsigned char* ws = (unsigned char*)d_ws;
    uint4* wpack          = (uint4*)ws;                        // 6 MB
    unsigned int* hbuf32  = (unsigned int*)(ws + 6291456);     // 512 KB tagged
    // total ws requirement: 6815744 bytes (~6.5 MiB)

    pack_kernel<<<64, 256, 0, stream>>>(w_rec, wpack);
    seed_kernel<<<256, 256, 0, stream>>>(hidden, hbuf32);
    gru_kernel<<<256, 256, 0, stream>>>(x, hidden, w_in, b_in, b_rec,
                                        wpack, out, hbuf32);
}

// Round 7
// 1162.490 us; speedup vs baseline: 1.1547x; 1.1547x over previous
//
#include <hip/hip_runtime.h>

// GRU encoder: B=64, T=256, U=1024, VOCAB=10000. All float tensors are FP32.
// GEMM on bf16 MFMA (RNE-converted inputs); h carry stays exact f32 in a
// per-thread register. ONE persistent kernel; W_rec fragments resident in
// registers for all 256 steps. Cross-block handoff: SINGLE-WORD tagged
// publish {step_tag:16 | bf16(h):16}, sc0 sc1 write-through, no fences.
//
// Round-7 change: MONOTONE STICKY POLL. R4's poll re-loaded the full
// 16 MB/step A-broadcast every spin iteration -> LLC/fabric saturation
// (effective RT ~1.3 us vs ~0.4 unloaded; R5 measured a loaded RT at
// 0.78 us). Tags are monotone, so a quad that has matched tag t stays
// matched: pass 1 loads the full slice once (mandatory broadcast);
// re-poll iterations reload ONLY still-stale quads (per-lane pending
// mask, exec-masked loads). Spin traffic collapses ~50x; re-polls run
// at unloaded RT and the fabric stays clear for the publish stores.
// Every vmcnt(0) is followed by sched_barrier(0) (rule 18) so tag
// checks cannot be hoisted above the wait. No counted-vmcnt pipelining
// (R6's hang). Correctness rests only on: word atomicity of the tagged
// u32, tag monotonicity, and full-tag verification before consumption.
#define BB 64
#define TT 256
#define UU 1024
#define NG 3072

typedef __attribute__((ext_vector_type(8))) __bf16 bf16x8;
typedef __attribute__((ext_vector_type(4))) float f32x4;

__device__ __forceinline__ unsigned short f2bf(float f) {
    union { unsigned int i; float f; } c; c.f = f;
    unsigned int r = c.i + 0x7FFFu + ((c.i >> 16) & 1u);  // RNE
    return (unsigned short)(r >> 16);
}

__device__ __forceinline__ float fsigm(float xv) {
    // fast sigmoid: err ~1e-7 abs, far under the bf16 handoff quantization
    return __fdividef(1.f, 1.f + __expf(-xv));
}

union U16x8 { unsigned short us[8]; uint4 u4; };

// ---------------------------------------------------------------------------
// Pack W_rec (f32) into bf16 MFMA B-fragment order (unchanged, verified).
// Total 6 MB.
// ---------------------------------------------------------------------------
__global__ __launch_bounds__(256) void pack_kernel(
    const float* __restrict__ w_rec,    // (1024, 3072) f32
    uint4* __restrict__ wpack)
{
    const int tid  = threadIdx.x;
    const int kc   = tid >> 6;
    const int lane = tid & 63;
    const int l16  = lane & 15;
    const int quad = lane >> 4;
    const int cj   = blockIdx.x;            // 0..63
    const int colb = (cj << 4) + l16;

    #pragma unroll
    for (int g = 0; g < 3; ++g) {
        #pragma unroll
        for (int s = 0; s < 8; ++s) {
            const int kb = (kc << 8) + (s << 5) + (quad << 3);
            U16x8 c;
            #pragma unroll
            for (int j = 0; j < 8; ++j)
                c.us[j] = f2bf(w_rec[(size_t)(kb + j) * NG + g * UU + colb]);
            wpack[(size_t)(((cj * 4 + kc) * 24) + g * 8 + s) * 64 + lane] = c.u4;
        }
    }
}

// Seed: parity 0 = {tag 0 | bf16(hidden)}; parity 1 poisoned with tag 0xFFFF
// so graph replays never see a stale matching tag.
__global__ __launch_bounds__(256) void seed_kernel(
    const float* __restrict__ hidden,       // (64, 1024) f32
    unsigned int* __restrict__ hbuf32)
{
    const int i = blockIdx.x * 256 + threadIdx.x;   // 65536 elements
    hbuf32[i] = (unsigned int)f2bf(hidden[i]);      // tag 0 in high half
    hbuf32[BB * UU + i] = 0xFFFF0000u;              // invalid tag
}

// ---------------------------------------------------------------------------
// Persistent GRU kernel. 256 blocks x 256 threads, 1 block/CU.
// block = (ri, cj): ri = batch rowgroup (4 x 16 rows), cj = unit colgroup
// (64 x 16 cols). Waves K-split (4 x 256). Step t consumes parity t&1 words
// tagged t; step t produces parity (t+1)&1 words tagged t+1.
// ---------------------------------------------------------------------------
__global__ __launch_bounds__(256, 1) void gru_kernel(
    const int* __restrict__ x,              // (64, 256) int32
    const float* __restrict__ hidden,       // (64, 1024) f32
    const float* __restrict__ w_in,         // (10000, 3072) f32
    const float* __restrict__ b_in,         // (3072,) f32
    const float* __restrict__ b_rec,        // (3072,) f32
    const uint4* __restrict__ wpack,        // packed W_rec bf16 frags
    float* __restrict__ out,                // (64,256,1024) + (64,1024) f32
    unsigned int* __restrict__ hbuf32)      // ws: 2 x 64 x 1024 tagged u32
{
    const int tid  = threadIdx.x;
    const int wave = tid >> 6;        // K-chunk 0..3
    const int lane = tid & 63;
    const int l16  = lane & 15;
    const int quad = lane >> 4;

    const int ri   = blockIdx.x >> 6;  // 0..3
    const int cj   = blockIdx.x & 63;  // 0..63
    const int row0 = ri << 4;
    const int col0 = cj << 4;

    // parity-double-buffered K-reduction scratch (one barrier per step)
    __align__(16) __shared__ float red[2][4][3][64][4];   // 24 KB

    // ---- B-fragments: loaded ONCE, resident for all 256 steps ----
    const uint4* wp = wpack + (size_t)((cj * 4 + wave) * 24) * 64 + lane;
    uint4 wf[3][8];
    #pragma unroll
    for (int g = 0; g < 3; ++g)
        #pragma unroll
        for (int s = 0; s < 8; ++s)
            wf[g][s] = wp[(g * 8 + s) * 64];

    // ---- per-thread gate element (fixed for the whole sequence) ----
    const int em = tid >> 4;
    const int en = tid & 15;
    const int gb = row0 + em;
    const int gu = col0 + en;
    // C/D layout (col=lane&15, row=(lane>>4)*4+reg) -> source lane/reg
    const int rl = ((em >> 2) << 4) | en;
    const int rr = em & 3;

    // loop-invariant biases
    const float bz  = b_in[gu]          + b_rec[gu];
    const float br  = b_in[UU + gu]     + b_rec[UU + gu];
    const float bih = b_in[2 * UU + gu];
    const float brh = b_rec[2 * UU + gu];

    // exact f32 h carry in a register
    float h = hidden[gb * UU + gu];

    const int* xrow = x + gb * TT;

    const unsigned int* a0 = hbuf32 + (size_t)(row0 + l16) * UU
                           + (wave << 8) + (quad << 3);         // parity 0 A base
    const unsigned int* a1 = a0 + (size_t)BB * UU;              // parity 1
    unsigned int* hb0 = hbuf32 + (size_t)gb * UU + gu;          // parity 0 slot
    unsigned int* hb1 = hb0 + (size_t)BB * UU;                  // parity 1
    float* orow = out + (size_t)gb * TT * UU + gu;

    // embedding gather for t=0 (plain cached loads)
    size_t wrow = (size_t)xrow[0] * NG;
    float wz = w_in[wrow + gu];
    float wr = w_in[wrow + UU + gu];
    float wh = w_in[wrow + 2 * UU + gu];

    for (int t = 0; t < TT; ++t) {
        const unsigned int texp = (unsigned int)t << 16;
        const unsigned int* arow = (t & 1) ? a1 : a0;
        uint4 q[16];

        // ---- pass 1: full-slice load (the mandatory broadcast, paid once) ----
        #pragma unroll
        for (int s = 0; s < 8; ++s) {
            asm volatile("global_load_dwordx4 %0, %1, off sc0 sc1"
                         : "=v"(q[2 * s])     : "v"(arow + (s << 5)));
            asm volatile("global_load_dwordx4 %0, %1, off sc0 sc1"
                         : "=v"(q[2 * s + 1]) : "v"(arow + (s << 5) + 4));
        }
        asm volatile("s_waitcnt vmcnt(0)" ::: "memory");
        __builtin_amdgcn_sched_barrier(0);

        unsigned int pend = 0;
        #pragma unroll
        for (int i = 0; i < 16; ++i) {
            const unsigned int va = (q[i].x ^ texp) | (q[i].y ^ texp)
                                  | (q[i].z ^ texp) | (q[i].w ^ texp);
            if (va & 0xFFFF0000u) pend |= (1u << i);
        }

        // ---- sticky re-poll: reload ONLY still-stale quads (exec-masked).
        // Tag monotonicity: a matched quad stays matched forever. ----
        while (__builtin_amdgcn_ballot_w64(pend != 0u)) {
            #pragma unroll
            for (int i = 0; i < 16; ++i)
                if (pend & (1u << i))
                    asm volatile("global_load_dwordx4 %0, %1, off sc0 sc1"
                                 : "=v"(q[i])
                                 : "v"(arow + ((i >> 1) << 5) + ((i & 1) << 2)));
            asm volatile("s_waitcnt vmcnt(0)" ::: "memory");
            __builtin_amdgcn_sched_barrier(0);
            #pragma unroll
            for (int i = 0; i < 16; ++i)
                if (pend & (1u << i)) {
                    const unsigned int va = (q[i].x ^ texp) | (q[i].y ^ texp)
                                          | (q[i].z ^ texp) | (q[i].w ^ texp);
                    if (!(va & 0xFFFF0000u)) pend &= ~(1u << i);
                }
        }
        __builtin_amdgcn_sched_barrier(0);

        // ---- pack low halves into MFMA A fragments (v_perm: 1 op/word) ----
        f32x4 acc0 = {0.f, 0.f, 0.f, 0.f};
        f32x4 acc1 = {0.f, 0.f, 0.f, 0.f};
        f32x4 acc2 = {0.f, 0.f, 0.f, 0.f};
        #pragma unroll
        for (int s = 0; s < 8; ++s) {
            const uint4 lo = q[2 * s];
            const uint4 hi = q[2 * s + 1];
            uint4 aw;
            aw.x = __builtin_amdgcn_perm(lo.y, lo.x, 0x05040100u);
            aw.y = __builtin_amdgcn_perm(lo.w, lo.z, 0x05040100u);
            aw.z = __builtin_amdgcn_perm(hi.y, hi.x, 0x05040100u);
            aw.w = __builtin_amdgcn_perm(hi.w, hi.z, 0x05040100u);
            const bf16x8 a = __builtin_bit_cast(bf16x8, aw);
            acc0 = __builtin_amdgcn_mfma_f32_16x16x32_bf16(
                a, __builtin_bit_cast(bf16x8, wf[0][s]), acc0, 0, 0, 0);
            acc1 = __builtin_amdgcn_mfma_f32_16x16x32_bf16(
                a, __builtin_bit_cast(bf16x8, wf[1][s]), acc1, 0, 0, 0);
            acc2 = __builtin_amdgcn_mfma_f32_16x16x32_bf16(
                a, __builtin_bit_cast(bf16x8, wf[2][s]), acc2, 0, 0, 0);
        }

        // ---- cross-wave K reduction through LDS (parity-buffered) ----
        const int p = t & 1;
        *(f32x4*)&red[p][wave][0][lane][0] = acc0;
        *(f32x4*)&red[p][wave][1][lane][0] = acc1;
        *(f32x4*)&red[p][wave][2][lane][0] = acc2;
        __syncthreads();

        const float rz = red[p][0][0][rl][rr] + red[p][1][0][rl][rr]
                       + red[p][2][0][rl][rr] + red[p][3][0][rl][rr];
        const float rrv = red[p][0][1][rl][rr] + red[p][1][1][rl][rr]
                        + red[p][2][1][rl][rr] + red[p][3][1][rl][rr];
        const float rh = red[p][0][2][rl][rr] + red[p][1][2][rl][rr]
                       + red[p][2][2][rl][rr] + red[p][3][2][rl][rr];

        // fast gates (publish chain): sigmoid via __expf, tanh = 2*sigm(2x)-1
        const float z  = fsigm(wz + rz + bz);
        const float r  = fsigm(wr + rrv + br);
        const float th = wh + bih + r * (rh + brh);
        const float hh = 2.f * fsigm(2.f * th) - 1.f;
        h = z * h + (1.f - z) * hh;

        // ---- publish FIRST (critical path): single tagged word, no drain ----
        if (t < TT - 1) {
            const unsigned int hv = (texp + 0x10000u)
                                  | (unsigned int)f2bf(h);
            unsigned int* hs = (t & 1) ? hb0 : hb1;   // parity (t+1)&1
            asm volatile("global_store_dword %0, %1, off sc0 sc1"
                         :: "v"(hs), "v"(hv) : "memory");
        }

        // ---- background: out row + next embedding gather (off the chain) ----
        orow[(size_t)t * UU] = h;
        if (t < TT - 1) {
            wrow = (size_t)xrow[t + 1] * NG;
            wz = w_in[wrow + gu];
            wr = w_in[wrow + UU + gu];
            wh = w_in[wrow + 2 * UU + gu];
        }
    }

    // final state
    out[(size_t)BB * TT * UU + (size_t)gb * UU + gu] = h;
}

extern "C" void kernel_launch(void* const* d_in, const int* in_sizes, int n_in,
                              void* d_out, int out_size, void* d_ws, size_t ws_size,
                              hipStream_t stream) {
    const int* x        = (const int*)d_in[0];
    const float* hidden = (const float*)d_in[1];
    const float* w_in   = (const float*)d_in[2];
    const float* w_rec  = (const float*)d_in[3];
    const float* b_in   = (const float*)d_in[4];
    const float* b_rec  = (const float*)d_in[5];
    float* out          = (float*)d_out;

    unsigned char* ws = (unsigned char*)d_ws;
    uint4* wpack          = (uint4*)ws;                        // 6 MB
    unsigned int* hbuf32  = (unsigned int*)(ws + 6291456);     // 512 KB tagged
    // total ws requirement: 6815744 bytes (~6.5 MiB)

    pack_kernel<<<64, 256, 0, stream>>>(w_rec, wpack);
    seed_kernel<<<256, 256, 0, stream>>>(hidden, hbuf32);
    gru_kernel<<<256, 256, 0, stream>>>(x, hidden, w_in, b_in, b_rec,
                                        wpack, out, hbuf32);
}